// Round 5
// baseline (771.632 us; speedup 1.0000x reference)
//
#include <hip/hip_runtime.h>
#include <hip/hip_bf16.h>
#include <cstdint>

#define B_   32
#define CIN  12
#define L_   1024
#define T_   64
#define C1_  64
#define C2_  128
#define K_   7
#define PAD_ 3

typedef __attribute__((ext_vector_type(8))) short short8;
typedef __attribute__((ext_vector_type(4))) float float4v;

// ---- workspace layout (bytes) ----
// s1T : bf16 [B][L][half(2)][T][32]  = 268,435,456   (c1 PERMUTED within each 32: pos = kq*8+e*4+r)
// w2hi: bf16 A-frag-linear            = 114,688
// w1f : bf16 A-frag-linear [cp2][ks4][mf4][lane64][j8] = 32,768
// pool: f32  [B][C2]                  = 16,384   (fused avg-pool accumulator, zeroed by K0a)
#define WS_S1T   0ull
#define WS_W2HI  268435456ull
#define WS_W1F   (WS_W2HI + 114688ull)
#define WS_POOL  (WS_W1F + 32768ull)

static __device__ __forceinline__ ushort bf16_hi(float f) {
    __hip_bfloat16 h = __float2bfloat16(f);
    ushort u; __builtin_memcpy(&u, &h, 2); return u;
}
static __device__ __forceinline__ float bf16_back(ushort u) {
    __hip_bfloat16 h; __builtin_memcpy(&h, &u, 2); return __bfloat162float(h);
}

// ---------------- K0a: w2 -> bf16, A-fragment-linear layout (+ zero pool) ----------------
__global__ __launch_bounds__(256) void k0_prep_w2(const float* __restrict__ w2,
                                                  ushort* __restrict__ w2hi,
                                                  float* __restrict__ pool) {
    int i = blockIdx.x * 256 + threadIdx.x;
    if (i < B_ * C2_) pool[i] = 0.0f;            // stream-ordered before K2's atomics
    if (i >= C2_ * K_ * C1_) return;
    int c2 = i / (K_ * C1_);
    int r_ = i % (K_ * C1_);
    int kk = r_ / C1_;
    int c1 = r_ % C1_;
    float w = w2[(c2 * C1_ + c1) * K_ + kk];
    ushort uh = bf16_hi(w);
    int h    = c1 >> 5;
    int c1r  = c1 & 31;
    int e    = c1r >> 4;
    int kq   = (c1r >> 2) & 3;
    int rr   = c1r & 3;
    int j    = e * 4 + rr;
    int mt   = c2 >> 4;
    int lane = kq * 16 + (c2 & 15);
    int o    = ((((kk * 2 + h) * 8 + mt) * 64) + lane) * 8 + j;
    w2hi[o] = uh;
}

// ---------------- K0b: w1 -> bf16 hi/lo, A-fragment-linear for conv1 MFMA ----------------
__global__ __launch_bounds__(256) void k0_prep_w1(const float* __restrict__ w1,
                                                  ushort* __restrict__ w1f) {
    int i = blockIdx.x * 256 + threadIdx.x;      // [cp2][ks4][mf4][lane64][j8] = 16384
    if (i >= 16384) return;
    int j    = i & 7;
    int lane = (i >> 3) & 63;
    int mf   = (i >> 9) & 3;
    int ks   = (i >> 11) & 3;
    int cp   = i >> 13;
    int k    = ks * 32 + (lane >> 4) * 8 + j;
    int dl   = k >> 4;
    int slot = k & 15;
    int c1   = mf * 16 + (lane & 15);
    float v  = (slot < CIN && dl < K_) ? w1[(c1 * CIN + slot) * K_ + dl] : 0.0f;
    ushort hi = bf16_hi(v);
    float  rem = v - bf16_back(hi);
    ushort lo = bf16_hi(rem);
    w1f[i] = cp ? lo : hi;
}

// ---------------- K1: conv1 via bf16 MFMA (hi/lo split) + LIF1 spike -> s1t ----------------
// (unchanged — 4 waves, wave = one l, register-direct permuted s1t store)
__global__ __launch_bounds__(256, 2) void k1_conv1_mfma(const float* __restrict__ x,
                                                        const ushort* __restrict__ w1f,
                                                        const float* __restrict__ b1,
                                                        ushort* __restrict__ s1t) {
    __shared__ __align__(16) ushort S[10 * 2048];    // 40,960 B
    int tid  = threadIdx.x;
    int lane = tid & 63;
    int wl   = tid >> 6;
    int b    = blockIdx.y;
    int bx   = blockIdx.x;
    int swz  = ((bx & 7) << 5) | (bx >> 3);          // XCD swizzle, bijective (256 = 8*32)
    int lb   = swz * 4;

    #pragma unroll
    for (int it = 0; it < 5; ++it) {
        int u  = it * 256 + tid;                     // 10*2*64 = 1280 exactly
        int t  = u & 63;
        int h2 = (u >> 6) & 1;
        int lp = u >> 7;
        int gl = lb + lp - PAD_;
        bool ok = (gl >= 0) && (gl < L_);
        short8 hv, lv;
        #pragma unroll
        for (int jj = 0; jj < 8; ++jj) {
            int cin = h2 * 8 + jj;
            float v = (ok && cin < CIN)
                ? x[(((size_t)b * CIN + cin) * L_ + gl) * T_ + t] : 0.0f;
            ushort hb = bf16_hi(v);
            ushort lo = bf16_hi(v - bf16_back(hb));
            hv[jj] = (short)hb;
            lv[jj] = (short)lo;
        }
        int nt = t >> 4, t15 = t & 15;
        int base = lp * 2048 + nt * 256 + h2 * 128 + t15 * 8;
        *(short8*)&S[base]        = hv;              // cp=0 (hi)
        *(short8*)&S[base + 1024] = lv;              // cp=1 (lo)
    }
    __syncthreads();

    int t15 = lane & 15;
    int h2l = (lane >> 4) & 1;
    int kqh = lane >> 5;

    float4v acc[4][4];                               // constant indices ONLY
    #pragma unroll
    for (int i = 0; i < 4; ++i)
        #pragma unroll
        for (int jn = 0; jn < 4; ++jn)
            acc[i][jn] = (float4v){0.0f, 0.0f, 0.0f, 0.0f};

    #pragma unroll
    for (int ks = 0; ks < 4; ++ks) {
        int dtap = ks * 2 + kqh;
        int lpr  = (dtap == 7) ? 0 : (wl + dtap);    // dl==7: A is zero, row 0 is finite
        int rb   = lpr * 2048 + h2l * 128 + t15 * 8;
        short8 bh[4], bl[4];
        #pragma unroll
        for (int nt = 0; nt < 4; ++nt) {
            bh[nt] = *(const short8*)&S[rb + nt * 256];
            bl[nt] = *(const short8*)&S[rb + nt * 256 + 1024];
        }
        #pragma unroll
        for (int mf = 0; mf < 4; ++mf) {
            const ushort* ap = w1f + ((size_t)(ks * 4 + mf) * 64 + lane) * 8;
            short8 ah = *(const short8*)ap;
            short8 al = *(const short8*)(ap + 8192);     // cp=1 half
            #pragma unroll
            for (int nt = 0; nt < 4; ++nt) {
                acc[mf][nt] = __builtin_amdgcn_mfma_f32_16x16x32_bf16(ah, bh[nt], acc[mf][nt], 0, 0, 0);
                acc[mf][nt] = __builtin_amdgcn_mfma_f32_16x16x32_bf16(al, bh[nt], acc[mf][nt], 0, 0, 0);
                acc[mf][nt] = __builtin_amdgcn_mfma_f32_16x16x32_bf16(ah, bl[nt], acc[mf][nt], 0, 0, 0);
            }
        }
    }

    // spike <=> conv + b1 >= TH1/GAIN = 0.25 (LIF1 tau=1 is memoryless).
    int l  = lb + wl;
    int kq = lane >> 4;
    #pragma unroll
    for (int h = 0; h < 2; ++h) {
        float4v be0 = *(const float4v*)&b1[h * 32 + kq * 4];
        float4v be1 = *(const float4v*)&b1[h * 32 + 16 + kq * 4];
        #pragma unroll
        for (int nt = 0; nt < 4; ++nt) {
            uint s0 = (acc[2 * h][nt][0] + be0[0] >= 0.25f) ? 0x3F80u : 0u;
            uint s1 = (acc[2 * h][nt][1] + be0[1] >= 0.25f) ? 0x3F80u : 0u;
            uint s2 = (acc[2 * h][nt][2] + be0[2] >= 0.25f) ? 0x3F80u : 0u;
            uint s3 = (acc[2 * h][nt][3] + be0[3] >= 0.25f) ? 0x3F80u : 0u;
            uint s4 = (acc[2 * h + 1][nt][0] + be1[0] >= 0.25f) ? 0x3F80u : 0u;
            uint s5 = (acc[2 * h + 1][nt][1] + be1[1] >= 0.25f) ? 0x3F80u : 0u;
            uint s6 = (acc[2 * h + 1][nt][2] + be1[2] >= 0.25f) ? 0x3F80u : 0u;
            uint s7 = (acc[2 * h + 1][nt][3] + be1[3] >= 0.25f) ? 0x3F80u : 0u;
            uint4 u4 = { s0 | (s1 << 16), s2 | (s3 << 16),
                         s4 | (s5 << 16), s6 | (s7 << 16) };
            size_t off = ((((size_t)b * L_ + l) * 2 + h) * T_ + (nt * 16 + t15)) * 32 + kq * 8;
            *(uint4*)&s1t[off] = u4;
        }
    }
}

// ---------------- K2: conv2 (bf16 MFMA) + fused LIF2 + fused avg-pool ----------------
// R5: zero-barrier global-direct (R4 mechanism) with the two R4 failures fixed:
//  (1) launch_bounds(256,3) -> reg cap ~170; R4's (256,4)=128 cap spilled ~40B/thread
//      (WRITE_SIZE 180MB). Tripwire: WRITE_SIZE must be ~16MB this round.
//  (2) explicit 2-slot software pipeline: named register groups (slot A = a*/bv*,
//      slot B = c*/dv*), prefetch segment s+2 issued AFTER the MFMAs that free the
//      slot -> 1 full segment (~230 cyc across 3 waves/SIMD) of latency cover.
//      All buffers statically indexed (scratch-demotion invariant).
// Segment s = h*7+kk, s = 0..13. B-frag = coalesced 1KB run of s1t; A-frag = w2hi
// (L2-resident). s_setprio(1) around MFMA clusters (T5: barrier-free staggered waves).
// INVARIANT: acc[][] indexed with compile-time constants ONLY.
#define K2_LOADB(B0, B1, B2, B3, SEG) do {                                        \
    int _gl = l + ((SEG) % 7) - PAD_;                                             \
    if (_gl >= 0 && _gl < L_) {                                                   \
        const ushort* _row = &s1t[(((size_t)b * L_ + _gl) * 2 + ((SEG) / 7)) * 2048]; \
        B0 = *(const short8*)&_row[boff];                                         \
        B1 = *(const short8*)&_row[512 + boff];                                   \
        B2 = *(const short8*)&_row[1024 + boff];                                  \
        B3 = *(const short8*)&_row[1536 + boff];                                  \
    } else {                                                                      \
        B0 = (short8){0,0,0,0,0,0,0,0}; B1 = (short8){0,0,0,0,0,0,0,0};           \
        B2 = (short8){0,0,0,0,0,0,0,0}; B3 = (short8){0,0,0,0,0,0,0,0};           \
    } } while (0)

#define K2_LOADA(A0, A1, A2, A3, SEG) do {                                        \
    const ushort* _ab = &w2hi[((((SEG) % 7) * 2 + (SEG) / 7) * 8 + wm * 4) * 512 + lane * 8]; \
    A0 = *(const short8*)&_ab[0];                                                 \
    A1 = *(const short8*)&_ab[512];                                               \
    A2 = *(const short8*)&_ab[1024];                                              \
    A3 = *(const short8*)&_ab[1536];                                              \
    } while (0)

#define K2_MFMA16(A0, A1, A2, A3, B0, B1, B2, B3) do {                            \
    __builtin_amdgcn_s_setprio(1);                                                \
    acc[0][0] = __builtin_amdgcn_mfma_f32_16x16x32_bf16(A0, B0, acc[0][0], 0,0,0); \
    acc[0][1] = __builtin_amdgcn_mfma_f32_16x16x32_bf16(A0, B1, acc[0][1], 0,0,0); \
    acc[0][2] = __builtin_amdgcn_mfma_f32_16x16x32_bf16(A0, B2, acc[0][2], 0,0,0); \
    acc[0][3] = __builtin_amdgcn_mfma_f32_16x16x32_bf16(A0, B3, acc[0][3], 0,0,0); \
    acc[1][0] = __builtin_amdgcn_mfma_f32_16x16x32_bf16(A1, B0, acc[1][0], 0,0,0); \
    acc[1][1] = __builtin_amdgcn_mfma_f32_16x16x32_bf16(A1, B1, acc[1][1], 0,0,0); \
    acc[1][2] = __builtin_amdgcn_mfma_f32_16x16x32_bf16(A1, B2, acc[1][2], 0,0,0); \
    acc[1][3] = __builtin_amdgcn_mfma_f32_16x16x32_bf16(A1, B3, acc[1][3], 0,0,0); \
    acc[2][0] = __builtin_amdgcn_mfma_f32_16x16x32_bf16(A2, B0, acc[2][0], 0,0,0); \
    acc[2][1] = __builtin_amdgcn_mfma_f32_16x16x32_bf16(A2, B1, acc[2][1], 0,0,0); \
    acc[2][2] = __builtin_amdgcn_mfma_f32_16x16x32_bf16(A2, B2, acc[2][2], 0,0,0); \
    acc[2][3] = __builtin_amdgcn_mfma_f32_16x16x32_bf16(A2, B3, acc[2][3], 0,0,0); \
    acc[3][0] = __builtin_amdgcn_mfma_f32_16x16x32_bf16(A3, B0, acc[3][0], 0,0,0); \
    acc[3][1] = __builtin_amdgcn_mfma_f32_16x16x32_bf16(A3, B1, acc[3][1], 0,0,0); \
    acc[3][2] = __builtin_amdgcn_mfma_f32_16x16x32_bf16(A3, B2, acc[3][2], 0,0,0); \
    acc[3][3] = __builtin_amdgcn_mfma_f32_16x16x32_bf16(A3, B3, acc[3][3], 0,0,0); \
    __builtin_amdgcn_s_setprio(0);                                                \
    } while (0)

#define K2_STEP_A(SEG, PF) do {                                                   \
    K2_MFMA16(a0, a1, a2, a3, bv0, bv1, bv2, bv3);                                \
    if (PF) { K2_LOADA(a0, a1, a2, a3, (SEG) + 2); K2_LOADB(bv0, bv1, bv2, bv3, (SEG) + 2); } \
    } while (0)

#define K2_STEP_B(SEG, PF) do {                                                   \
    K2_MFMA16(c0, c1, c2, c3, dv0, dv1, dv2, dv3);                                \
    if (PF) { K2_LOADA(c0, c1, c2, c3, (SEG) + 2); K2_LOADB(dv0, dv1, dv2, dv3, (SEG) + 2); } \
    } while (0)

__global__ __launch_bounds__(256, 3) void k2_conv2_lif(const ushort* __restrict__ s1t,
                                                       const ushort* __restrict__ w2hi,
                                                       const float* __restrict__ b2,
                                                       float* __restrict__ pool) {
    __shared__ __align__(16) float E_all[4 * 1088];   // 17,408 B, wave-private slices
    int tid    = threadIdx.x;
    int wv     = tid >> 6;
    int lane   = tid & 63;
    int wm     = wv >> 1;          // m half: c2 in [wm*64, wm*64+64)
    int wn     = wv & 1;           // n half: l = lb + wn
    int b      = blockIdx.y;
    int bx     = blockIdx.x;
    int swz    = ((bx & 7) << 6) | (bx >> 3);   // bijective XCD swizzle (512 = 8*64)
    int lb     = swz * 2;
    int l      = lb + wn;
    int lane15 = lane & 15;
    int kq     = lane >> 4;
    int boff   = lane15 * 32 + kq * 8;          // B-frag lane offset within 1KB run (ushorts)

    float4v acc[4][4];             // [m-frag][n-frag], 64 regs — constant indices ONLY
    #pragma unroll
    for (int i = 0; i < 4; ++i)
        #pragma unroll
        for (int j = 0; j < 4; ++j)
            acc[i][j] = (float4v){0.0f, 0.0f, 0.0f, 0.0f};

    short8 a0, a1, a2, a3, bv0, bv1, bv2, bv3;    // slot A
    short8 c0, c1, c2, c3, dv0, dv1, dv2, dv3;    // slot B

    K2_LOADA(a0, a1, a2, a3, 0); K2_LOADB(bv0, bv1, bv2, bv3, 0);
    K2_LOADA(c0, c1, c2, c3, 1); K2_LOADB(dv0, dv1, dv2, dv3, 1);

    K2_STEP_A(0, 1);  K2_STEP_B(1, 1);
    K2_STEP_A(2, 1);  K2_STEP_B(3, 1);
    K2_STEP_A(4, 1);  K2_STEP_B(5, 1);
    K2_STEP_A(6, 1);  K2_STEP_B(7, 1);
    K2_STEP_A(8, 1);  K2_STEP_B(9, 1);
    K2_STEP_A(10, 1); K2_STEP_B(11, 1);
    K2_STEP_A(12, 0); K2_STEP_B(13, 0);

    // ---- epilogue: streaming transpose (one nt = 16 t-rows at a time) + LIF2 scan ----
    // E[t15 16][68]: b128 stores slot=(lane15+kq+4mfl)%8 -> 8 lanes/slot, conflict-free;
    // reads bank (4t+lane)%32 -> 2-way (free). All 64 lanes scan (c2 = wm*64 + lane).
    // Scan: v' = A*v + (E*Cs + D), A = 1-1/0.9, Cs = 2/0.9, D = bias*2/0.9.
    // Wave-private region -> only lgkmcnt waits, no __syncthreads.
    float* E = E_all + wv * 1088;    // 16*68*4 = 4,352 B per wave
    int c2v = wm * 64 + lane;
    const float Af = 1.0f - 1.0f / 0.9f;
    const float Cs = 2.0f / 0.9f;
    float D = b2[c2v] * Cs;
    float v = 0.0f;
    uint cnt = 0u;
    #pragma unroll
    for (int nt = 0; nt < 4; ++nt) {
        *(float4v*)&E[lane15 * 68 + 0 * 16 + kq * 4] = acc[0][nt];   // D: col t = nt*16+lane15
        *(float4v*)&E[lane15 * 68 + 1 * 16 + kq * 4] = acc[1][nt];   //    row c2l = mfl*16+kq*4+r
        *(float4v*)&E[lane15 * 68 + 2 * 16 + kq * 4] = acc[2][nt];
        *(float4v*)&E[lane15 * 68 + 3 * 16 + kq * 4] = acc[3][nt];
        __builtin_amdgcn_s_waitcnt(0);           // wave-local LDS RAW
        #pragma unroll
        for (int tt = 0; tt < 16; ++tt) {
            float e = fmaf(E[tt * 68 + lane], Cs, D);
            v = fmaf(Af, v, e);
            bool sp = (v >= 0.5f);
            cnt += sp ? 1u : 0u;
            v = sp ? 0.0f : v;
        }
        __builtin_amdgcn_s_waitcnt(0);           // reads done before next nt overwrites
    }
    atomicAdd(&pool[b * C2_ + c2v], (float)cnt);  // integer-valued: exact, order-free
}

// ---------------- K3: fc on pooled [B][C2] (pool already summed over l,t) ----------------
__global__ __launch_bounds__(128) void k3_fc(const float* __restrict__ pool,
                                             const float* __restrict__ fcw,
                                             const float* __restrict__ fcb,
                                             float* __restrict__ out) {
    int i = threadIdx.x;          // 128 = B*4 outputs
    int b = i >> 2, c = i & 3;
    float o = fcb[c];
    #pragma unroll 8
    for (int c2 = 0; c2 < C2_; ++c2)
        o = fmaf(fcw[c * C2_ + c2], pool[b * C2_ + c2] * (1.0f / 65536.0f), o);
    out[b * 4 + c] = o;
}

extern "C" void kernel_launch(void* const* d_in, const int* in_sizes, int n_in,
                              void* d_out, int out_size, void* d_ws, size_t ws_size,
                              hipStream_t stream) {
    const float* x   = (const float*)d_in[0];
    const float* w1  = (const float*)d_in[1];
    const float* b1  = (const float*)d_in[2];
    const float* w2  = (const float*)d_in[3];
    const float* b2  = (const float*)d_in[4];
    const float* fcw = (const float*)d_in[5];
    const float* fcb = (const float*)d_in[6];
    float* out = (float*)d_out;

    char* ws = (char*)d_ws;
    ushort* s1t  = (ushort*)(ws + WS_S1T);
    ushort* w2h  = (ushort*)(ws + WS_W2HI);
    ushort* w1f  = (ushort*)(ws + WS_W1F);
    float*  pool = (float*)(ws + WS_POOL);

    k0_prep_w2<<<dim3((C2_ * K_ * C1_ + 255) / 256), dim3(256), 0, stream>>>(w2, w2h, pool);
    k0_prep_w1<<<dim3(64), dim3(256), 0, stream>>>(w1, w1f);
    k1_conv1_mfma<<<dim3(L_ / 4, B_), dim3(256), 0, stream>>>(x, w1f, b1, s1t);
    k2_conv2_lif<<<dim3(L_ / 2, B_), dim3(256), 0, stream>>>(s1t, w2h, b2, pool);
    k3_fc<<<dim3(1), dim3(128), 0, stream>>>(pool, fcw, fcb, out);
}

// Round 6
// 524.948 us; speedup vs baseline: 1.4699x; 1.4699x over previous
//
#include <hip/hip_runtime.h>
#include <hip/hip_bf16.h>
#include <cstdint>

#define B_   32
#define CIN  12
#define L_   1024
#define T_   64
#define C1_  64
#define C2_  128
#define K_   7
#define PAD_ 3

typedef __attribute__((ext_vector_type(8))) short short8;
typedef __attribute__((ext_vector_type(4))) float float4v;

// ---- workspace layout (bytes) ----
// s1T : bf16 [B][L][half(2)][T][32]  = 268,435,456   (c1 PERMUTED within each 32: pos = kq*8+e*4+r)
// w2hi: bf16 A-frag-linear            = 114,688
// w1f : bf16 A-frag-linear [cp2][ks4][mf4][lane64][j8] = 32,768
// pool: f32  [B][C2]                  = 16,384   (fused avg-pool accumulator, zeroed by K0a)
#define WS_S1T   0ull
#define WS_W2HI  268435456ull
#define WS_W1F   (WS_W2HI + 114688ull)
#define WS_POOL  (WS_W1F + 32768ull)

static __device__ __forceinline__ ushort bf16_hi(float f) {
    __hip_bfloat16 h = __float2bfloat16(f);
    ushort u; __builtin_memcpy(&u, &h, 2); return u;
}
static __device__ __forceinline__ float bf16_back(ushort u) {
    __hip_bfloat16 h; __builtin_memcpy(&h, &u, 2); return __bfloat162float(h);
}

// ---------------- K0a: w2 -> bf16, A-fragment-linear layout (+ zero pool) ----------------
__global__ __launch_bounds__(256) void k0_prep_w2(const float* __restrict__ w2,
                                                  ushort* __restrict__ w2hi,
                                                  float* __restrict__ pool) {
    int i = blockIdx.x * 256 + threadIdx.x;
    if (i < B_ * C2_) pool[i] = 0.0f;            // stream-ordered before K2's atomics
    if (i >= C2_ * K_ * C1_) return;
    int c2 = i / (K_ * C1_);
    int r_ = i % (K_ * C1_);
    int kk = r_ / C1_;
    int c1 = r_ % C1_;
    float w = w2[(c2 * C1_ + c1) * K_ + kk];
    ushort uh = bf16_hi(w);
    int h    = c1 >> 5;
    int c1r  = c1 & 31;
    int e    = c1r >> 4;
    int kq   = (c1r >> 2) & 3;
    int rr   = c1r & 3;
    int j    = e * 4 + rr;
    int mt   = c2 >> 4;
    int lane = kq * 16 + (c2 & 15);
    int o    = ((((kk * 2 + h) * 8 + mt) * 64) + lane) * 8 + j;
    w2hi[o] = uh;
}

// ---------------- K0b: w1 -> bf16 hi/lo, A-fragment-linear for conv1 MFMA ----------------
__global__ __launch_bounds__(256) void k0_prep_w1(const float* __restrict__ w1,
                                                  ushort* __restrict__ w1f) {
    int i = blockIdx.x * 256 + threadIdx.x;      // [cp2][ks4][mf4][lane64][j8] = 16384
    if (i >= 16384) return;
    int j    = i & 7;
    int lane = (i >> 3) & 63;
    int mf   = (i >> 9) & 3;
    int ks   = (i >> 11) & 3;
    int cp   = i >> 13;
    int k    = ks * 32 + (lane >> 4) * 8 + j;
    int dl   = k >> 4;
    int slot = k & 15;
    int c1   = mf * 16 + (lane & 15);
    float v  = (slot < CIN && dl < K_) ? w1[(c1 * CIN + slot) * K_ + dl] : 0.0f;
    ushort hi = bf16_hi(v);
    float  rem = v - bf16_back(hi);
    ushort lo = bf16_hi(rem);
    w1f[i] = cp ? lo : hi;
}

// ---------------- K1: conv1 via bf16 MFMA (hi/lo split) + LIF1 spike -> s1t ----------------
// (unchanged — 4 waves, wave = one l, register-direct permuted s1t store)
__global__ __launch_bounds__(256, 2) void k1_conv1_mfma(const float* __restrict__ x,
                                                        const ushort* __restrict__ w1f,
                                                        const float* __restrict__ b1,
                                                        ushort* __restrict__ s1t) {
    __shared__ __align__(16) ushort S[10 * 2048];    // 40,960 B
    int tid  = threadIdx.x;
    int lane = tid & 63;
    int wl   = tid >> 6;
    int b    = blockIdx.y;
    int bx   = blockIdx.x;
    int swz  = ((bx & 7) << 5) | (bx >> 3);          // XCD swizzle, bijective (256 = 8*32)
    int lb   = swz * 4;

    #pragma unroll
    for (int it = 0; it < 5; ++it) {
        int u  = it * 256 + tid;                     // 10*2*64 = 1280 exactly
        int t  = u & 63;
        int h2 = (u >> 6) & 1;
        int lp = u >> 7;
        int gl = lb + lp - PAD_;
        bool ok = (gl >= 0) && (gl < L_);
        short8 hv, lv;
        #pragma unroll
        for (int jj = 0; jj < 8; ++jj) {
            int cin = h2 * 8 + jj;
            float v = (ok && cin < CIN)
                ? x[(((size_t)b * CIN + cin) * L_ + gl) * T_ + t] : 0.0f;
            ushort hb = bf16_hi(v);
            ushort lo = bf16_hi(v - bf16_back(hb));
            hv[jj] = (short)hb;
            lv[jj] = (short)lo;
        }
        int nt = t >> 4, t15 = t & 15;
        int base = lp * 2048 + nt * 256 + h2 * 128 + t15 * 8;
        *(short8*)&S[base]        = hv;              // cp=0 (hi)
        *(short8*)&S[base + 1024] = lv;              // cp=1 (lo)
    }
    __syncthreads();

    int t15 = lane & 15;
    int h2l = (lane >> 4) & 1;
    int kqh = lane >> 5;

    float4v acc[4][4];                               // constant indices ONLY
    #pragma unroll
    for (int i = 0; i < 4; ++i)
        #pragma unroll
        for (int jn = 0; jn < 4; ++jn)
            acc[i][jn] = (float4v){0.0f, 0.0f, 0.0f, 0.0f};

    #pragma unroll
    for (int ks = 0; ks < 4; ++ks) {
        int dtap = ks * 2 + kqh;
        int lpr  = (dtap == 7) ? 0 : (wl + dtap);    // dl==7: A is zero, row 0 is finite
        int rb   = lpr * 2048 + h2l * 128 + t15 * 8;
        short8 bh[4], bl[4];
        #pragma unroll
        for (int nt = 0; nt < 4; ++nt) {
            bh[nt] = *(const short8*)&S[rb + nt * 256];
            bl[nt] = *(const short8*)&S[rb + nt * 256 + 1024];
        }
        #pragma unroll
        for (int mf = 0; mf < 4; ++mf) {
            const ushort* ap = w1f + ((size_t)(ks * 4 + mf) * 64 + lane) * 8;
            short8 ah = *(const short8*)ap;
            short8 al = *(const short8*)(ap + 8192);     // cp=1 half
            #pragma unroll
            for (int nt = 0; nt < 4; ++nt) {
                acc[mf][nt] = __builtin_amdgcn_mfma_f32_16x16x32_bf16(ah, bh[nt], acc[mf][nt], 0, 0, 0);
                acc[mf][nt] = __builtin_amdgcn_mfma_f32_16x16x32_bf16(al, bh[nt], acc[mf][nt], 0, 0, 0);
                acc[mf][nt] = __builtin_amdgcn_mfma_f32_16x16x32_bf16(ah, bl[nt], acc[mf][nt], 0, 0, 0);
            }
        }
    }

    // spike <=> conv + b1 >= TH1/GAIN = 0.25 (LIF1 tau=1 is memoryless).
    int l  = lb + wl;
    int kq = lane >> 4;
    #pragma unroll
    for (int h = 0; h < 2; ++h) {
        float4v be0 = *(const float4v*)&b1[h * 32 + kq * 4];
        float4v be1 = *(const float4v*)&b1[h * 32 + 16 + kq * 4];
        #pragma unroll
        for (int nt = 0; nt < 4; ++nt) {
            uint s0 = (acc[2 * h][nt][0] + be0[0] >= 0.25f) ? 0x3F80u : 0u;
            uint s1 = (acc[2 * h][nt][1] + be0[1] >= 0.25f) ? 0x3F80u : 0u;
            uint s2 = (acc[2 * h][nt][2] + be0[2] >= 0.25f) ? 0x3F80u : 0u;
            uint s3 = (acc[2 * h][nt][3] + be0[3] >= 0.25f) ? 0x3F80u : 0u;
            uint s4 = (acc[2 * h + 1][nt][0] + be1[0] >= 0.25f) ? 0x3F80u : 0u;
            uint s5 = (acc[2 * h + 1][nt][1] + be1[1] >= 0.25f) ? 0x3F80u : 0u;
            uint s6 = (acc[2 * h + 1][nt][2] + be1[2] >= 0.25f) ? 0x3F80u : 0u;
            uint s7 = (acc[2 * h + 1][nt][3] + be1[3] >= 0.25f) ? 0x3F80u : 0u;
            uint4 u4 = { s0 | (s1 << 16), s2 | (s3 << 16),
                         s4 | (s5 << 16), s6 | (s7 << 16) };
            size_t off = ((((size_t)b * L_ + l) * 2 + h) * T_ + (nt * 16 + t15)) * 32 + kq * 8;
            *(uint4*)&s1t[off] = u4;
        }
    }
}

// ---------------- K2: conv2 (bf16 MFMA) + fused LIF2 + fused avg-pool ----------------
// R6: R3's proven inner loop/epilogue (compiler keeps it in regs, WRITE=16MB, 0 conflicts),
// consolidated to a 4-l block: 512 threads / 8 waves, wave = R3's exact role (one l x one
// 64-c2 half, acc[4][4], ~120 unified regs -> 2 blocks/CU = 16 waves/CU). Amortization vs
// R3 per l: stage rows 4 -> 2.5, barriers 2 -> 1.25, exposed stage drains 1 -> 0.5.
// R4/R5 lesson: hipcc spills hand-held global-direct pipelines (WRITE 180/494MB) — stay
// with LDS staging + barriers. Tripwire this round: WRITE_SIZE must stay ~16MB.
// INVARIANT: acc[][] indexed with compile-time constants ONLY (scratch-demotion hazard).
__global__ __launch_bounds__(512, 2) void k2_conv2_lif(const ushort* __restrict__ s1t,
                                                       const ushort* __restrict__ w2hi,
                                                       const float* __restrict__ b2,
                                                       float* __restrict__ pool) {
    __shared__ __align__(16) unsigned char lds_raw[40960];
    ushort* S = (ushort*)lds_raw;   // stage: [lp10][nt4][kq4][t15 16][j8] = 40,960 B (one h)
    int tid    = threadIdx.x;
    int wv     = tid >> 6;          // 0..7
    int lane   = tid & 63;
    int wn     = wv >> 1;           // l offset 0..3: l = lb + wn
    int wm     = wv & 1;            // m half: c2 in [wm*64, wm*64+64)
    int b      = blockIdx.y;
    int bx     = blockIdx.x;
    int swz    = ((bx & 7) << 5) | (bx >> 3);   // bijective XCD swizzle (256 = 8*32)
    int lb     = swz * 4;
    int lane15 = lane & 15;
    int kq     = lane >> 4;

    float4v acc[4][4];             // [m-frag][n-frag], 64 regs — constant indices ONLY
    #pragma unroll
    for (int i = 0; i < 4; ++i)
        #pragma unroll
        for (int j = 0; j < 4; ++j)
            acc[i][j] = (float4v){0.0f, 0.0f, 0.0f, 0.0f};

    #pragma unroll 1
    for (int h = 0; h < 2; ++h) {
        __syncthreads();           // S reads of previous h done
        // stage S = s1T[b][lb-3 .. lb+6][h][t][0..31]; 640 rows of 64 B
        #pragma unroll
        for (int it = 0; it < 2; ++it) {
            int u = it * 512 + tid;          // 0..1023; active < 640
            if (u < 640) {
                int lp = u >> 6, t = u & 63;
                int gl = lb + lp - PAD_;
                uint4 v0 = {0,0,0,0}, v1 = {0,0,0,0}, v2 = {0,0,0,0}, v3 = {0,0,0,0};
                if (gl >= 0 && gl < L_) {
                    const uint4* q = (const uint4*)&s1t[((((size_t)b * L_ + gl) * 2 + h) * T_) * 32 + (size_t)t * 32];
                    v0 = q[0]; v1 = q[1]; v2 = q[2]; v3 = q[3];
                }
                int nt = t >> 4, t15 = t & 15;
                int base = lp * 2048 + nt * 512 + t15 * 8;
                *(uint4*)&S[base]       = v0;
                *(uint4*)&S[base + 128] = v1;
                *(uint4*)&S[base + 256] = v2;
                *(uint4*)&S[base + 384] = v3;
            }
        }
        __syncthreads();
        #pragma unroll 2
        for (int kk = 0; kk < K_; ++kk) {
            int lp = wn + kk;            // staged row feeding output l = lb+wn at tap kk
            short8 bf[4];
            #pragma unroll
            for (int nt = 0; nt < 4; ++nt)   // lane-linear 2KB frag -> conflict-free b128
                bf[nt] = *(const short8*)&S[lp * 2048 + nt * 512 + lane * 8];
            #pragma unroll
            for (int mf = 0; mf < 4; ++mf) {
                int aoff = (((kk * 2 + h) * 8 + wm * 4 + mf) * 64 + lane) * 8;  // 32-bit
                short8 ahi = *(const short8*)&w2hi[aoff];
                #pragma unroll
                for (int nt = 0; nt < 4; ++nt)
                    acc[mf][nt] = __builtin_amdgcn_mfma_f32_16x16x32_bf16(ahi, bf[nt], acc[mf][nt], 0, 0, 0);
            }
        }
    }
    __syncthreads();    // all S reads done before epilogue overlays the region

    // ---- epilogue: streaming transpose (one nt = 16 t-rows at a time) + LIF2 scan ----
    // E[t15 16][68]: b128 stores slot=(lane15+kq+4mfl)%8 -> 8 lanes/slot, conflict-free;
    // reads bank (4t+lane)%32 -> 2-way (free). All 64 lanes scan (c2 = wm*64 + lane).
    // Scan: v' = A*v + (E*Cs + D), A = 1-1/0.9, Cs = 2/0.9, D = bias*2/0.9.
    // 8 waves x 4,352 B = 34,816 B overlaid on the 40,960 B stage region.
    float* E = ((float*)lds_raw) + wv * 1088;
    int c2v = wm * 64 + lane;
    const float Af = 1.0f - 1.0f / 0.9f;
    const float Cs = 2.0f / 0.9f;
    float D = b2[c2v] * Cs;
    float v = 0.0f;
    uint cnt = 0u;
    #pragma unroll
    for (int nt = 0; nt < 4; ++nt) {
        *(float4v*)&E[lane15 * 68 + 0 * 16 + kq * 4] = acc[0][nt];   // D: col t = nt*16+lane15
        *(float4v*)&E[lane15 * 68 + 1 * 16 + kq * 4] = acc[1][nt];   //    row c2l = mfl*16+kq*4+r
        *(float4v*)&E[lane15 * 68 + 2 * 16 + kq * 4] = acc[2][nt];
        *(float4v*)&E[lane15 * 68 + 3 * 16 + kq * 4] = acc[3][nt];
        __builtin_amdgcn_s_waitcnt(0);           // wave-local LDS RAW
        #pragma unroll
        for (int tt = 0; tt < 16; ++tt) {
            float e = fmaf(E[tt * 68 + lane], Cs, D);
            v = fmaf(Af, v, e);
            bool sp = (v >= 0.5f);
            cnt += sp ? 1u : 0u;
            v = sp ? 0.0f : v;
        }
        __builtin_amdgcn_s_waitcnt(0);           // reads done before next nt overwrites
    }
    atomicAdd(&pool[b * C2_ + c2v], (float)cnt);  // integer-valued: exact, order-free
}

// ---------------- K3: fc on pooled [B][C2] (pool already summed over l,t) ----------------
__global__ __launch_bounds__(128) void k3_fc(const float* __restrict__ pool,
                                             const float* __restrict__ fcw,
                                             const float* __restrict__ fcb,
                                             float* __restrict__ out) {
    int i = threadIdx.x;          // 128 = B*4 outputs
    int b = i >> 2, c = i & 3;
    float o = fcb[c];
    #pragma unroll 8
    for (int c2 = 0; c2 < C2_; ++c2)
        o = fmaf(fcw[c * C2_ + c2], pool[b * C2_ + c2] * (1.0f / 65536.0f), o);
    out[b * 4 + c] = o;
}

extern "C" void kernel_launch(void* const* d_in, const int* in_sizes, int n_in,
                              void* d_out, int out_size, void* d_ws, size_t ws_size,
                              hipStream_t stream) {
    const float* x   = (const float*)d_in[0];
    const float* w1  = (const float*)d_in[1];
    const float* b1  = (const float*)d_in[2];
    const float* w2  = (const float*)d_in[3];
    const float* b2  = (const float*)d_in[4];
    const float* fcw = (const float*)d_in[5];
    const float* fcb = (const float*)d_in[6];
    float* out = (float*)d_out;

    char* ws = (char*)d_ws;
    ushort* s1t  = (ushort*)(ws + WS_S1T);
    ushort* w2h  = (ushort*)(ws + WS_W2HI);
    ushort* w1f  = (ushort*)(ws + WS_W1F);
    float*  pool = (float*)(ws + WS_POOL);

    k0_prep_w2<<<dim3((C2_ * K_ * C1_ + 255) / 256), dim3(256), 0, stream>>>(w2, w2h, pool);
    k0_prep_w1<<<dim3(64), dim3(256), 0, stream>>>(w1, w1f);
    k1_conv1_mfma<<<dim3(L_ / 4, B_), dim3(256), 0, stream>>>(x, w1f, b1, s1t);
    k2_conv2_lif<<<dim3(L_ / 4, B_), dim3(512), 0, stream>>>(s1t, w2h, b2, pool);
    k3_fc<<<dim3(1), dim3(128), 0, stream>>>(pool, fcw, fcb, out);
}